// Round 9
// baseline (34.947 us; speedup 1.0000x reference)
//
#include <hip/hip_runtime.h>
#include <hip/hip_bf16.h>
#include <math.h>

#define NB_TASKS 20
#define CLASSES_PER_TASK 100
#define N_COLS (NB_TASKS * CLASSES_PER_TASK)   // 2000
#define N_F4   (N_COLS / 4)                    // 500
#define F4_PER_TASK (CLASSES_PER_TASK / 4)     // 25
#define INV_TEMP (1.0f / 5.0f)
#define ROWS_PER_BLOCK 4

typedef float vf4 __attribute__((ext_vector_type(4)));

__device__ __forceinline__ float rfl_f(float x) {
    return __int_as_float(__builtin_amdgcn_readfirstlane(__float_as_int(x)));
}

struct Top2 { int j1, j2; float w1, w2; };

// v: lane t (t<20) holds value for task t; lanes 20..63 hold -INF.
// Returns wave-uniform top-2 indices and softmax weights (scaled by coef).
__device__ __forceinline__ Top2 softmax_top2(float v, float coef, int lane) {
    // argmax, min-index tiebreak (== jax top_k tie rule); data lives in lanes 0..31
    float v1 = v; int i1 = lane;
    #pragma unroll
    for (int off = 16; off; off >>= 1) {
        float ov = __shfl_xor(v1, off);
        int   oj = __shfl_xor(i1, off);
        if (ov > v1 || (ov == v1 && oj < i1)) { v1 = ov; i1 = oj; }
    }
    // second argmax, excluding lane i1
    float v2 = (lane == i1) ? -INFINITY : v;
    int   i2 = lane;
    #pragma unroll
    for (int off = 16; off; off >>= 1) {
        float ov = __shfl_xor(v2, off);
        int   oj = __shfl_xor(i2, off);
        if (ov > v2 || (ov == v2 && oj < i2)) { v2 = ov; i2 = oj; }
    }
    // softmax denominator: exp((v - max)/T); -INF lanes contribute 0
    float ex  = __expf((v - v1) * INV_TEMP);
    float sum = ex;
    #pragma unroll
    for (int off = 16; off; off >>= 1)
        sum += __shfl_xor(sum, off);

    Top2 r;
    r.j1 = __builtin_amdgcn_readfirstlane(i1);
    r.j2 = __builtin_amdgcn_readfirstlane(i2);
    float w1 = coef / sum;                        // exp(0) = 1
    float w2 = __expf((v2 - v1) * INV_TEMP) * w1;
    r.w1 = rfl_f(w1);
    r.w2 = rfl_f(w2);
    return r;
}

// ---------- kernel 1: pure-read reduction -> per-row weight vector ----------
__global__ __launch_bounds__(256) void weights_kernel(
    const float* __restrict__ gol,     // [B, 20]
    const float* __restrict__ gocls,   // [B, 2000]
    const float* __restrict__ alpha_p, // [1]
    float* __restrict__ wout,          // [B, 20] workspace
    int B)
{
    const int tid  = threadIdx.x;
    const int lane = tid & 63;
    const int b    = blockIdx.x * ROWS_PER_BLOCK + (tid >> 6);
    if (b >= B) return;

    const int grp = lane >> 4;   // 16-lane group: 0..3
    const int s   = lane & 15;

    const float* grow = gocls + (size_t)b * N_COLS;

    const float a  = alpha_p[0];
    const float gv = (lane < NB_TASKS) ? gol[(size_t)b * NB_TASKS + lane] : -INFINITY;

    // per-task max over 100 classes, 4 tasks per iteration
    float cv = -INFINITY;
    #pragma unroll
    for (int k = 0; k < 5; ++k) {
        const vf4* p = (const vf4*)(grow + (4 * k + grp) * CLASSES_PER_TASK);
        vf4 v0 = p[s];
        float m = fmaxf(fmaxf(v0.x, v0.y), fmaxf(v0.z, v0.w));
        if (s < 25 - 16) {
            vf4 v1 = p[16 + s];
            m = fmaxf(m, fmaxf(fmaxf(v1.x, v1.y), fmaxf(v1.z, v1.w)));
        }
        #pragma unroll
        for (int off = 8; off; off >>= 1)          // butterfly within 16-lane group
            m = fmaxf(m, __shfl_xor(m, off));
        float g2 = __shfl(m, (lane & 3) << 4);     // lane 4k+g <- group g's max
        if ((lane >> 2) == k) cv = g2;             // lanes 0..19 collect task maxes
    }

    const Top2 pa = softmax_top2(gv, a,        lane);
    const Top2 pb = softmax_top2(cv, 1.0f - a, lane);

    // combined per-task weight (duplicates sum naturally)
    float w = 0.0f;
    w += (lane == pa.j1) ? pa.w1 : 0.0f;
    w += (lane == pa.j2) ? pa.w2 : 0.0f;
    w += (lane == pb.j1) ? pb.w1 : 0.0f;
    w += (lane == pb.j2) ? pb.w2 : 0.0f;

    if (lane < NB_TASKS) wout[(size_t)b * NB_TASKS + lane] = w;
}

// ---------- kernel 2: pure-streaming apply (single write per element) ----------
__global__ __launch_bounds__(256) void apply_kernel(
    const float* __restrict__ win,     // [B, 20] weights
    const float* __restrict__ dol,     // [B, 2000]
    float* __restrict__ out,           // [B, 2000]
    int B)
{
    const int tid  = threadIdx.x;
    const int lane = tid & 63;
    const int b    = blockIdx.x * ROWS_PER_BLOCK + (tid >> 6);
    if (b >= B) return;

    // lane t<20 holds this row's weight for task t
    const float wv = (lane < NB_TASKS) ? win[(size_t)b * NB_TASKS + lane] : 0.0f;

    const vf4* din  = (const vf4*)(dol + (size_t)b * N_COLS);
    vf4*       dout = (vf4*)(out + (size_t)b * N_COLS);

    #pragma unroll
    for (int i = 0; i < (N_F4 + 63) / 64; ++i) {
        const int f = lane + 64 * i;
        if (f < N_F4) {
            const float w = __shfl(wv, f / F4_PER_TASK);   // f/25 -> task weight
            vf4 r = {0.0f, 0.0f, 0.0f, 0.0f};
            if (w != 0.0f) r = din[f] * w;
            __builtin_nontemporal_store(r, &dout[f]);
        }
    }
}

extern "C" void kernel_launch(void* const* d_in, const int* in_sizes, int n_in,
                              void* d_out, int out_size, void* d_ws, size_t ws_size,
                              hipStream_t stream) {
    const float* gol   = (const float*)d_in[0];
    const float* gocls = (const float*)d_in[1];
    const float* dol   = (const float*)d_in[2];
    const float* alpha = (const float*)d_in[3];
    float* out = (float*)d_out;
    float* wbuf = (float*)d_ws;            // B*20 floats = 640 KB

    const int B = in_sizes[0] / NB_TASKS;  // 8192

    const int grid = (B + ROWS_PER_BLOCK - 1) / ROWS_PER_BLOCK;
    hipLaunchKernelGGL(weights_kernel, dim3(grid), dim3(256), 0, stream,
                       gol, gocls, alpha, wbuf, B);
    hipLaunchKernelGGL(apply_kernel, dim3(grid), dim3(256), 0, stream,
                       wbuf, dol, out, B);
}

// Round 10
// 27.903 us; speedup vs baseline: 1.2524x; 1.2524x over previous
//
#include <hip/hip_runtime.h>
#include <hip/hip_bf16.h>
#include <math.h>

#define NB_TASKS 20
#define CLASSES_PER_TASK 100
#define N_COLS (NB_TASKS * CLASSES_PER_TASK)   // 2000
#define N_F4   (N_COLS / 4)                    // 500
#define F4_PER_TASK (CLASSES_PER_TASK / 4)     // 25
#define INV_TEMP (1.0f / 5.0f)
#define ROWS_PER_BLOCK 4

typedef float vf4 __attribute__((ext_vector_type(4)));

__device__ __forceinline__ float rfl_f(float x) {
    return __int_as_float(__builtin_amdgcn_readfirstlane(__float_as_int(x)));
}

struct Top2 { int j1, j2; float w1, w2; };

// v: lane t (t<20) holds value for task t; lanes 20..63 hold -INF.
// Returns wave-uniform top-2 indices and softmax weights (scaled by coef).
__device__ __forceinline__ Top2 softmax_top2(float v, float coef, int lane) {
    // argmax, min-index tiebreak (== jax top_k tie rule); data lives in lanes 0..31
    float v1 = v; int i1 = lane;
    #pragma unroll
    for (int off = 16; off; off >>= 1) {
        float ov = __shfl_xor(v1, off);
        int   oj = __shfl_xor(i1, off);
        if (ov > v1 || (ov == v1 && oj < i1)) { v1 = ov; i1 = oj; }
    }
    // second argmax, excluding lane i1
    float v2 = (lane == i1) ? -INFINITY : v;
    int   i2 = lane;
    #pragma unroll
    for (int off = 16; off; off >>= 1) {
        float ov = __shfl_xor(v2, off);
        int   oj = __shfl_xor(i2, off);
        if (ov > v2 || (ov == v2 && oj < i2)) { v2 = ov; i2 = oj; }
    }
    // softmax denominator: exp((v - max)/T); -INF lanes contribute 0
    float ex  = __expf((v - v1) * INV_TEMP);
    float sum = ex;
    #pragma unroll
    for (int off = 16; off; off >>= 1)
        sum += __shfl_xor(sum, off);

    Top2 r;
    r.j1 = __builtin_amdgcn_readfirstlane(i1);
    r.j2 = __builtin_amdgcn_readfirstlane(i2);
    float w1 = coef / sum;                        // exp(0) = 1
    float w2 = __expf((v2 - v1) * INV_TEMP) * w1;
    r.w1 = rfl_f(w1);
    r.w2 = rfl_f(w2);
    return r;
}

__global__ __launch_bounds__(256) void mix_kernel(
    const float* __restrict__ gol,     // [B, 20]
    const float* __restrict__ gocls,   // [B, 2000]
    const float* __restrict__ dol,     // [B, 2000]
    const float* __restrict__ alpha_p, // [1]
    float* __restrict__ out,           // [B, 2000]
    int B)
{
    const int tid  = threadIdx.x;
    const int lane = tid & 63;
    const int b    = blockIdx.x * ROWS_PER_BLOCK + (tid >> 6);
    if (b >= B) return;

    const int grp  = lane >> 4;   // 16-lane group: 0..3 (reduce phase)
    const int s    = lane & 15;
    const int half = lane >> 5;   // 32-lane half: 0..1 (packed topk phase)
    const int hs   = lane & 31;

    const vf4*   din  = (const vf4*)(dol + (size_t)b * N_COLS);
    vf4*         dout = (vf4*)(out + (size_t)b * N_COLS);
    const float* grow = gocls + (size_t)b * N_COLS;

    // --- ISSUE ALL 10 REDUCE LOADS FIRST: one base address, immediate
    //     offsets; 10 x dwordx4 in flight (~40 VGPR) = max per-wave MLP. ---
    // group g handles tasks 4k+g; second load made fully dense: lanes s>=9
    // re-read p[0] (in-range, redundant, harmless for max).
    const vf4* p0 = (const vf4*)(grow + grp * CLASSES_PER_TASK);
    const int  s2 = (s < 9) ? 16 + s : 0;
    vf4 va0 = p0[s +  0 * F4_PER_TASK * 4 / 4];  // k=0 .. laid out via constant idx
    vf4 va1 = p0[s + 100];                        // k=1: 4*100 floats = 100 f4
    vf4 va2 = p0[s + 200];
    vf4 va3 = p0[s + 300];
    vf4 va4 = p0[s + 400];
    vf4 vb0 = p0[s2 +   0];
    vf4 vb1 = p0[s2 + 100];
    vf4 vb2 = p0[s2 + 200];
    vf4 vb3 = p0[s2 + 300];
    vf4 vb4 = p0[s2 + 400];

    // --- path A (gol): tiny load + shuffle chains, overlaps reduce loads ---
    const float a  = alpha_p[0];
    const float gv = (lane < NB_TASKS) ? gol[(size_t)b * NB_TASKS + lane] : -INFINITY;
    const Top2 pa = softmax_top2(gv, a, lane);

    // packed A-pair dol load: half 0 -> region pa.j1, half 1 -> pa.j2
    const int jA = half ? pa.j2 : pa.j1;
    vf4 dA = {0,0,0,0};
    if (hs < F4_PER_TASK) dA = din[jA * F4_PER_TASK + hs];

    // --- dense branch-free zero-blast of the whole row (NT stores) ---
    {
        const vf4 z = {0.0f, 0.0f, 0.0f, 0.0f};
        #pragma unroll
        for (int i = 0; i < (N_F4 + 63) / 64; ++i) {
            const int f = lane + 64 * i;
            if (f < N_F4) __builtin_nontemporal_store(z, &dout[f]);
        }
    }

    // --- reduce the 10 preloaded vectors: per-task max, 4 tasks/iter ---
    float cv = -INFINITY;
    vf4 vas[5] = {va0, va1, va2, va3, va4};
    vf4 vbs[5] = {vb0, vb1, vb2, vb3, vb4};
    #pragma unroll
    for (int k = 0; k < 5; ++k) {
        vf4 x = vas[k], y = vbs[k];
        float m = fmaxf(fmaxf(fmaxf(x.x, x.y), fmaxf(x.z, x.w)),
                        fmaxf(fmaxf(y.x, y.y), fmaxf(y.z, y.w)));
        #pragma unroll
        for (int off = 8; off; off >>= 1)          // butterfly within 16-lane group
            m = fmaxf(m, __shfl_xor(m, off));
        float g2 = __shfl(m, (lane & 3) << 4);     // lane 4k+g <- group g's max
        if ((lane >> 2) == k) cv = g2;             // lanes 0..19 collect task maxes
    }

    // --- path B (per-task gocls max) ---
    const Top2 pb = softmax_top2(cv, 1.0f - a, lane);

    // fold B weights into A where indices coincide
    const float wA1 = pa.w1 + ((pb.j1 == pa.j1) ? pb.w1 : 0.0f)
                            + ((pb.j2 == pa.j1) ? pb.w2 : 0.0f);
    const float wA2 = pa.w2 + ((pb.j1 == pa.j2) ? pb.w1 : 0.0f)
                            + ((pb.j2 == pa.j2) ? pb.w2 : 0.0f);
    const bool bo1 = (pb.j1 != pa.j1) && (pb.j1 != pa.j2);
    const bool bo2 = (pb.j2 != pa.j1) && (pb.j2 != pa.j2);

    const float wA = half ? wA2 : wA1;
    const int   jB = half ? pb.j2 : pb.j1;
    const float wB = half ? pb.w2 : pb.w1;
    const bool  bo = half ? bo2 : bo1;

    // packed B-pair dol load (one instruction, <=50 lanes)
    vf4 dB = {0,0,0,0};
    if (bo && hs < F4_PER_TASK) dB = din[jB * F4_PER_TASK + hs];

    // blast zeros must land before overwriting top-k regions
    asm volatile("s_waitcnt vmcnt(0)" ::: "memory");

    // packed tail stores: 2 instructions cover up to 4 regions
    if (hs < F4_PER_TASK) {
        __builtin_nontemporal_store(dA * wA, &dout[jA * F4_PER_TASK + hs]);
        if (bo)
            __builtin_nontemporal_store(dB * wB, &dout[jB * F4_PER_TASK + hs]);
    }
}

extern "C" void kernel_launch(void* const* d_in, const int* in_sizes, int n_in,
                              void* d_out, int out_size, void* d_ws, size_t ws_size,
                              hipStream_t stream) {
    const float* gol   = (const float*)d_in[0];
    const float* gocls = (const float*)d_in[1];
    const float* dol   = (const float*)d_in[2];
    const float* alpha = (const float*)d_in[3];
    float* out = (float*)d_out;

    const int B = in_sizes[0] / NB_TASKS;  // 8192

    const int grid = (B + ROWS_PER_BLOCK - 1) / ROWS_PER_BLOCK;
    hipLaunchKernelGGL(mix_kernel, dim3(grid), dim3(256), 0, stream,
                       gol, gocls, dol, alpha, out, B);
}